// Round 13
// baseline (163.036 us; speedup 1.0000x reference)
//
#include <hip/hip_runtime.h>
#include <math.h>

#define S_LEN 1024
#define B_SZ 4
#define E_DIM 1024
#define H_NUM 16
#define HD 64
#define IDX_MAX 2044   // clip(dist,-1022,1022)+1022 in [0,2044]
#define NEG_BIG (-3.0e38f)

typedef __attribute__((ext_vector_type(8))) short s16x8;   // 8 bf16 (4 VGPRs)
typedef __attribute__((ext_vector_type(4))) float f32x4;

__device__ __forceinline__ unsigned short f2bf(float f) {
  union { float f; unsigned int u; } v; v.f = f;
  return (unsigned short)((v.u + 0x7FFFu + ((v.u >> 16) & 1u)) >> 16);  // RNE
}
__device__ __forceinline__ float bf2f(unsigned short h) {
  union { unsigned int u; float f; } v; v.u = ((unsigned int)h) << 16;
  return v.f;
}
__device__ __forceinline__ void gload16(const void* g, void* l) {
  __builtin_amdgcn_global_load_lds(
      (const __attribute__((address_space(1))) void*)g,
      (__attribute__((address_space(3))) void*)l, 16, 0, 0);
}
__device__ __forceinline__ int clampg(int g) {
  return g < 0 ? 0 : (g > IDX_MAX ? IDX_MAX : g);
}

// ---- DPP 16-lane rotation butterfly reduces (VALU pipe, not LDS) ----------
template <int CTRL>
__device__ __forceinline__ float dppror(float x) {
  union { float f; int i; } a, b;
  a.f = x;
  b.i = __builtin_amdgcn_update_dpp(a.i, a.i, CTRL, 0xF, 0xF, false);
  return b.f;
}
__device__ __forceinline__ float rmax16(float x) {
  x = fmaxf(x, dppror<0x128>(x));
  x = fmaxf(x, dppror<0x124>(x));
  x = fmaxf(x, dppror<0x122>(x));
  x = fmaxf(x, dppror<0x121>(x));
  return x;
}
__device__ __forceinline__ float rsum16(float x) {
  x += dppror<0x128>(x);
  x += dppror<0x124>(x);
  x += dppror<0x122>(x);
  x += dppror<0x121>(x);
  return x;
}

// ---------------------------------------------------------------------------
// All fp32->bf16 conversions in one launch (8 segments).  [validated R4-R12]
// ---------------------------------------------------------------------------
__global__ __launch_bounds__(256) void conv_all(
    const float* __restrict__ q, const float* __restrict__ k,
    const float* __restrict__ v, const float* __restrict__ wq,
    const float* __restrict__ wk, const float* __restrict__ wv,
    const float* __restrict__ wo, const float* __restrict__ tb,
    unsigned short* __restrict__ oq, unsigned short* __restrict__ ok,
    unsigned short* __restrict__ ov, unsigned short* __restrict__ owq,
    unsigned short* __restrict__ owk, unsigned short* __restrict__ owv,
    unsigned short* __restrict__ owo, unsigned short* __restrict__ otb)
{
  const int b = blockIdx.x;
  const float* src; unsigned short* dst; int n, lb;
  if (b < 2048)      { src = q;  dst = oq;  n = 4194304; lb = b; }
  else if (b < 4096) { src = k;  dst = ok;  n = 4194304; lb = b - 2048; }
  else if (b < 6144) { src = v;  dst = ov;  n = 4194304; lb = b - 4096; }
  else if (b < 6656) { src = wq; dst = owq; n = 1048576; lb = b - 6144; }
  else if (b < 7168) { src = wk; dst = owk; n = 1048576; lb = b - 6656; }
  else if (b < 7680) { src = wv; dst = owv; n = 1048576; lb = b - 7168; }
  else if (b < 8192) { src = wo; dst = owo; n = 1048576; lb = b - 7680; }
  else               { src = tb; dst = otb; n = 131008;  lb = b - 8192; }
  const int i = (lb * 256 + threadIdx.x) << 3;
  if (i >= n) return;
  const float4 a = *(const float4*)(src + i);
  const float4 c = *(const float4*)(src + i + 4);
  union { unsigned short us[8]; uint4 v4; } u;
  u.us[0] = f2bf(a.x); u.us[1] = f2bf(a.y); u.us[2] = f2bf(a.z); u.us[3] = f2bf(a.w);
  u.us[4] = f2bf(c.x); u.us[5] = f2bf(c.y); u.us[6] = f2bf(c.z); u.us[7] = f2bf(c.w);
  *(uint4*)(dst + i) = u.v4;
}

// ---------------------------------------------------------------------------
// Fused QKV projection [validated R3-R12]: bf16 MFMA, 128x128 tile, BK=64.
// q-scale folds log2(e) (softmax runs in exp2 domain).
// ---------------------------------------------------------------------------
__global__ __launch_bounds__(256, 3) void qkv_mfma(
    const unsigned short* __restrict__ X0, const unsigned short* __restrict__ X1,
    const unsigned short* __restrict__ X2,
    const unsigned short* __restrict__ W0, const unsigned short* __restrict__ W1,
    const unsigned short* __restrict__ W2,
    const float* __restrict__ bp0, const float* __restrict__ bp1,
    const float* __restrict__ bp2,
    unsigned short* __restrict__ O0, unsigned short* __restrict__ O1,
    unsigned short* __restrict__ O2)
{
  __shared__ unsigned short As[128 * 64];
  __shared__ unsigned short Bs[128 * 64];

  const int z = blockIdx.z;
  const unsigned short* X = z == 0 ? X0 : (z == 1 ? X1 : X2);
  const unsigned short* W = z == 0 ? W0 : (z == 1 ? W1 : W2);
  const float* bias = z == 0 ? bp0 : (z == 1 ? bp1 : bp2);
  unsigned short* O = z == 0 ? O0 : (z == 1 ? O1 : O2);
  const float scale = z == 0 ? 0.18033688f : 1.0f;   // 0.125 * log2(e)

  const int tid = threadIdx.x;
  const int w = tid >> 6, l = tid & 63;
  const int l15 = l & 15, l4 = l >> 4;
  const int m0 = blockIdx.x << 7, n0 = blockIdx.y << 7;
  const int wr0 = (w >> 1) << 6, wc0 = (w & 1) << 6;

  f32x4 acc[4][4];
#pragma unroll
  for (int mt = 0; mt < 4; ++mt)
#pragma unroll
    for (int nt = 0; nt < 4; ++nt) acc[mt][nt] = (f32x4){0.f, 0.f, 0.f, 0.f};

  float bias4[4];
#pragma unroll
  for (int nt = 0; nt < 4; ++nt) bias4[nt] = bias[n0 + wc0 + (nt << 4) + l15];

  const int cbase = (w << 6) + l;

  for (int kt = 0; kt < 16; ++kt) {
    const int k0 = kt << 6;
    __syncthreads();
#pragma unroll
    for (int i = 0; i < 4; ++i) {
      const int c = cbase + (i << 8);
      const int r = c >> 3, kc = c & 7;
      char* ldsA = (char*)As + (((i << 2) + w) << 10);
      char* ldsB = (char*)Bs + (((i << 2) + w) << 10);
      gload16(X + (size_t)(m0 + r) * E_DIM + k0 + (kc << 3), ldsA);
      gload16(W + (size_t)(n0 + r) * E_DIM + k0 + (kc << 3), ldsB);
    }
    __syncthreads();
#pragma unroll
    for (int kh = 0; kh < 2; ++kh) {
      s16x8 af[4], bfr[4];
#pragma unroll
      for (int mt = 0; mt < 4; ++mt)
        af[mt] = *(const s16x8*)&As[(wr0 + (mt << 4) + l15) * 64 + (kh << 5) + (l4 << 3)];
#pragma unroll
      for (int nt = 0; nt < 4; ++nt)
        bfr[nt] = *(const s16x8*)&Bs[(wc0 + (nt << 4) + l15) * 64 + (kh << 5) + (l4 << 3)];
#pragma unroll
      for (int mt = 0; mt < 4; ++mt)
#pragma unroll
        for (int nt = 0; nt < 4; ++nt)
          acc[mt][nt] = __builtin_amdgcn_mfma_f32_16x16x32_bf16(
              af[mt], bfr[nt], acc[mt][nt], 0, 0, 0);
    }
  }

#pragma unroll
  for (int mt = 0; mt < 4; ++mt)
#pragma unroll
    for (int nt = 0; nt < 4; ++nt) {
      const int n = n0 + wc0 + (nt << 4) + l15;
      const int h = n >> 6, d = n & 63;
      const f32x4 c = acc[mt][nt];
#pragma unroll
      for (int r = 0; r < 4; ++r) {
        const int m = m0 + wr0 + (mt << 4) + (l4 << 2) + r;
        const int s = m >> 2, b = m & 3;
        O[((((size_t)b * H_NUM + h) * S_LEN) + s) * HD + d] =
            f2bf((c[r] + bias4[nt]) * scale);
      }
    }
}

// ---------------------------------------------------------------------------
// Output projection, single bf16 A [validated R10-R12].
// ---------------------------------------------------------------------------
__global__ __launch_bounds__(256) void outp_mfma(
    const unsigned short* __restrict__ A, const unsigned short* __restrict__ W,
    const float* __restrict__ bias, float* __restrict__ out)
{
  __shared__ unsigned short As[128 * 64];
  __shared__ unsigned short Bs[128 * 64];

  const int tid = threadIdx.x;
  const int w = tid >> 6, l = tid & 63;
  const int l15 = l & 15, l4 = l >> 4;
  const int m0 = blockIdx.x << 7, n0 = blockIdx.y << 7;
  const int wr0 = (w >> 1) << 6, wc0 = (w & 1) << 6;

  f32x4 acc[4][4];
#pragma unroll
  for (int mt = 0; mt < 4; ++mt)
#pragma unroll
    for (int nt = 0; nt < 4; ++nt) acc[mt][nt] = (f32x4){0.f, 0.f, 0.f, 0.f};

  float bias4[4];
#pragma unroll
  for (int nt = 0; nt < 4; ++nt) bias4[nt] = bias[n0 + wc0 + (nt << 4) + l15];

  const int cbase = (w << 6) + l;

  for (int kt = 0; kt < 16; ++kt) {
    const int k0 = kt << 6;
    __syncthreads();
#pragma unroll
    for (int i = 0; i < 4; ++i) {
      const int c = cbase + (i << 8);
      const int r = c >> 3, kc = c & 7;
      char* ldsA = (char*)As + (((i << 2) + w) << 10);
      char* ldsB = (char*)Bs + (((i << 2) + w) << 10);
      gload16(A + (size_t)(m0 + r) * E_DIM + k0 + (kc << 3), ldsA);
      gload16(W + (size_t)(n0 + r) * E_DIM + k0 + (kc << 3), ldsB);
    }
    __syncthreads();
#pragma unroll
    for (int kh = 0; kh < 2; ++kh) {
      s16x8 af[4], bfr[4];
      const int ko = (kh << 5) + (l4 << 3);
#pragma unroll
      for (int mt = 0; mt < 4; ++mt)
        af[mt] = *(const s16x8*)&As[(wr0 + (mt << 4) + l15) * 64 + ko];
#pragma unroll
      for (int nt = 0; nt < 4; ++nt)
        bfr[nt] = *(const s16x8*)&Bs[(wc0 + (nt << 4) + l15) * 64 + ko];
#pragma unroll
      for (int mt = 0; mt < 4; ++mt)
#pragma unroll
        for (int nt = 0; nt < 4; ++nt)
          acc[mt][nt] = __builtin_amdgcn_mfma_f32_16x16x32_bf16(
              af[mt], bfr[nt], acc[mt][nt], 0, 0, 0);
    }
  }

#pragma unroll
  for (int mt = 0; mt < 4; ++mt)
#pragma unroll
    for (int nt = 0; nt < 4; ++nt) {
      const int n = n0 + wc0 + (nt << 4) + l15;
      const f32x4 c = acc[mt][nt];
#pragma unroll
      for (int r = 0; r < 4; ++r) {
        const int m = m0 + wr0 + (mt << 4) + (l4 << 2) + r;
        const int b = m >> 10, s = m & 1023;
        out[((size_t)s * B_SZ + b) * E_DIM + n] = c[r] + bias4[nt];
      }
    }
}

// ---------------------------------------------------------------------------
// bf16 MFMA flash attention. R13 delta vs R12: diagonal ring keeps the b128
// gather, but columns are XOR-permuted per row (col' = i ^ (row&3)) to break
// the structural 8-way write conflict (enumerated: writes now exactly 2-way
// across all 32 banks). Reader un-permutes with a static-index cndmask
// butterfly (sw = (l15+3)&3, per-lane constant).
// ---------------------------------------------------------------------------
__global__ __launch_bounds__(256) void attn_mfma(
    const unsigned short* __restrict__ Qb, const unsigned short* __restrict__ Kb,
    const unsigned short* __restrict__ Vb, const unsigned short* __restrict__ Rb,
    unsigned short* __restrict__ AO)
{
  __shared__ unsigned short Ks[64 * 64];   // [j][d], slot = cb ^ (r&7)
  __shared__ unsigned short Rs[64 * 64];   // [r][d], slot = cb ^ (r&7)
  __shared__ unsigned short Vt[64 * 64];   // [d][j], slot = cb ^ (d&7) ^ ((d>>3)&7)
  __shared__ unsigned short Ps[64 * 64];   // [i][j], slot = cb ^ (i&7)
  __shared__ float ring2[128 * 68];        // band ring, diag-major, col-XOR'd

  const int tid = threadIdx.x;
  const int lane = tid & 63;
  const int w = tid >> 6;
  // XCD swizzle: all 16 s-blocks of a bh share bh%8's XCD (L2 locality).
  const int x = blockIdx.x;
  const int idx = x >> 3;
  const int bh = (x & 7) + ((idx & 7) << 3);   // 0..63
  const int st = idx >> 3;                     // 0..15
  const int s0 = st << 6;
  const int bb = bh >> 4, hh = bh & 15;
  const size_t base = (size_t)bh * (S_LEN * HD);
  const int l15 = lane & 15, l4 = lane >> 4;
  const int rb_ = w << 4;                 // wave's q-row base

  // staging maps
  const int sr = tid >> 3, scb = tid & 7;          // K/R rows, chunk
  const int ksl = (scb ^ (sr & 7)) << 3;           // swizzled chunk slot
  const int jp = tid >> 3, vc = tid & 7;           // V: j-pair, d-chunk
  const int jc = jp >> 2, jlow = (jp & 3) << 1;

  const int rbase = 959 - s0;

  // Q fragments (A-operand: row=lane&15, k=(lane>>4)*8+e)
  s16x8 qf0, qf1;
  {
    const unsigned short* qp =
        Qb + base + (size_t)(s0 + rb_ + l15) * HD + (l4 << 3);
    qf0 = *(const s16x8*)(qp);
    qf1 = *(const s16x8*)(qp + 32);
  }

  f32x4 of[4];
  float mrow[4], lrow[4];
#pragma unroll
  for (int m = 0; m < 4; ++m) {
    of[m] = (f32x4){0.f, 0.f, 0.f, 0.f};
    mrow[m] = NEG_BIG; lrow[m] = 0.f;
  }

  // band MFMA for block BP; ring write at row=(i+u)&127, col = i ^ (row&3)
#define BAND_MFMA(BP)                                                          \
  {                                                                            \
    f32x4 bq[4];                                                               \
    _Pragma("unroll") for (int rt = 0; rt < 4; ++rt)                           \
        bq[rt] = (f32x4){0.f, 0.f, 0.f, 0.f};                                  \
    __builtin_amdgcn_s_setprio(1);                                             \
    _Pragma("unroll") for (int kk = 0; kk < 2; ++kk) {                         \
      const s16x8 qv = kk ? qf1 : qf0;                                         \
      const int cb = l4 + (kk << 2);                                           \
      _Pragma("unroll") for (int rt = 0; rt < 4; ++rt) {                       \
        const int r = (rt << 4) + l15;                                         \
        const s16x8 rf = *(const s16x8*)&Rs[(r << 6) + ((cb ^ (r & 7)) << 3)]; \
        bq[rt] = __builtin_amdgcn_mfma_f32_16x16x32_bf16(qv, rf, bq[rt], 0, 0, 0); \
      }                                                                        \
    }                                                                          \
    __builtin_amdgcn_s_setprio(0);                                             \
    _Pragma("unroll") for (int rt = 0; rt < 4; ++rt) {                         \
      const int u_ = ((BP) << 6) + (rt << 4) + l15;                            \
      _Pragma("unroll") for (int m = 0; m < 4; ++m) {                          \
        const int irow_ = rb_ + (l4 << 2) + m;                                 \
        const int row_ = (irow_ + u_) & 127;                                   \
        ring2[row_ * 68 + (irow_ ^ (row_ & 3))] = bq[rt][m];                   \
      }                                                                        \
    }                                                                          \
  }

  // ---- prologue: band blocks 0 and 1
  s16x8 Kr0, Kr1, Vr0, Vr1, Rr0, Rr1;
  {
    s16x8 tA0, tA1, tB0, tB1;
    tA0 = *(const s16x8*)(Rb + (size_t)clampg(rbase + sr) * HD + (scb << 3));
    tA1 = *(const s16x8*)(Rb + (size_t)clampg(rbase + 32 + sr) * HD + (scb << 3));
    tB0 = *(const s16x8*)(Rb + (size_t)clampg(rbase + 64 + sr) * HD + (scb << 3));
    tB1 = *(const s16x8*)(Rb + (size_t)clampg(rbase + 96 + sr) * HD + (scb << 3));
    *(s16x8*)&Rs[(sr << 6) + ksl] = tA0;
    *(s16x8*)&Rs[((sr + 32) << 6) + ksl] = tA1;
    __syncthreads();
    BAND_MFMA(0);
    // prefetch tile 0 K,V and R block 2
    Kr0 = *(const s16x8*)(Kb + base + (size_t)sr * HD + (scb << 3));
    Kr1 = *(const s16x8*)(Kb + base + (size_t)(32 + sr) * HD + (scb << 3));
    Vr0 = *(const s16x8*)(Vb + base + (size_t)(jp << 1) * HD + (vc << 3));
    Vr1 = *(const s16x8*)(Vb + base + (size_t)((jp << 1) + 1) * HD + (vc << 3));
    Rr0 = *(const s16x8*)(Rb + (size_t)clampg(rbase + 128 + sr) * HD + (scb << 3));
    Rr1 = *(const s16x8*)(Rb + (size_t)clampg(rbase + 160 + sr) * HD + (scb << 3));
    __syncthreads();               // all waves done reading Rs (block 0)
    *(s16x8*)&Rs[(sr << 6) + ksl] = tB0;
    *(s16x8*)&Rs[((sr + 32) << 6) + ksl] = tB1;
    __syncthreads();
    BAND_MFMA(1);
  }

  for (int tt = 0; tt < 16; ++tt) {
    const int t0 = tt << 6;
    __syncthreads();   // previous compute (and prologue BAND(1)) done with LDS

    // ---- stage prefetched regs -> LDS
    *(s16x8*)&Ks[(sr << 6) + ksl] = Kr0;
    *(s16x8*)&Ks[((sr + 32) << 6) + ksl] = Kr1;
    *(s16x8*)&Rs[(sr << 6) + ksl] = Rr0;
    *(s16x8*)&Rs[((sr + 32) << 6) + ksl] = Rr1;
#pragma unroll
    for (int e = 0; e < 8; ++e) {
      const int d = (vc << 3) + e;
      const int slot = jc ^ e ^ vc;
      const unsigned int pack = (unsigned int)(unsigned short)Vr0[e] |
                                ((unsigned int)(unsigned short)Vr1[e] << 16);
      *(unsigned int*)&Vt[(d << 6) + (slot << 3) + jlow] = pack;
    }
    __syncthreads();

    // ---- prefetch next tile (K,V) and R block tt+3
    if (tt < 15) {
      const int tn = t0 + 64;
      Kr0 = *(const s16x8*)(Kb + base + (size_t)(tn + sr) * HD + (scb << 3));
      Kr1 = *(const s16x8*)(Kb + base + (size_t)(tn + sr + 32) * HD + (scb << 3));
      Vr0 = *(const s16x8*)(Vb + base + (size_t)(tn + (jp << 1)) * HD + (vc << 3));
      Vr1 = *(const s16x8*)(Vb + base + (size_t)(tn + (jp << 1) + 1) * HD + (vc << 3));
      const int gb = rbase + ((tt + 3) << 6) + sr;
      Rr0 = *(const s16x8*)(Rb + (size_t)clampg(gb) * HD + (scb << 3));
      Rr1 = *(const s16x8*)(Rb + (size_t)clampg(gb + 32) * HD + (scb << 3));
    }

    // ---- content MFMA
    f32x4 cf[4];
#pragma unroll
    for (int jt = 0; jt < 4; ++jt) cf[jt] = (f32x4){0.f, 0.f, 0.f, 0.f};
    __builtin_amdgcn_s_setprio(1);
#pragma unroll
    for (int kk = 0; kk < 2; ++kk) {
      const s16x8 qv = kk ? qf1 : qf0;
      const int cb = l4 + (kk << 2);
#pragma unroll
      for (int jt = 0; jt < 4; ++jt) {
        const int r = (jt << 4) + l15;
        const s16x8 kf = *(const s16x8*)&Ks[(r << 6) + ((cb ^ (r & 7)) << 3)];
        cf[jt] = __builtin_amdgcn_mfma_f32_16x16x32_bf16(qv, kf, cf[jt], 0, 0, 0);
      }
    }
    __builtin_amdgcn_s_setprio(0);

    // ---- band gather: b128 per jt, then static-index un-permute (m ^ sw)
    f32x4 gb4[4];
    {
      const int i0r = rb_ + (l4 << 2);
      const int sw = (l15 + 3) & 3;
      const bool sw0 = (sw & 1) != 0;
      const bool sw1 = (sw & 2) != 0;
#pragma unroll
      for (int jt = 0; jt < 4; ++jt) {
        const int v = (t0 + 63 + (jt << 4) + l15) & 127;
        const f32x4 ga = *(const f32x4*)&ring2[v * 68 + i0r];
        f32x4 tb, gg;
        tb[0] = sw0 ? ga[1] : ga[0];
        tb[1] = sw0 ? ga[0] : ga[1];
        tb[2] = sw0 ? ga[3] : ga[2];
        tb[3] = sw0 ? ga[2] : ga[3];
        gg[0] = sw1 ? tb[2] : tb[0];
        gg[1] = sw1 ? tb[3] : tb[1];
        gg[2] = sw1 ? tb[0] : tb[2];
        gg[3] = sw1 ? tb[1] : tb[3];
        gb4[jt] = gg;
      }
    }

    // ---- online softmax (exp2 domain); P -> LDS (own rows)
#pragma unroll
    for (int m = 0; m < 4; ++m) {
      const int irow = rb_ + (l4 << 2) + m;
      float sv[4];
#pragma unroll
      for (int jt = 0; jt < 4; ++jt)
        sv[jt] = cf[jt][m] + gb4[jt][m];
      float mx = fmaxf(fmaxf(sv[0], sv[1]), fmaxf(sv[2], sv[3]));
      mx = rmax16(mx);
      const float mnew = fmaxf(mrow[m], mx);
      const float alpha = exp2f(mrow[m] - mnew);
      float p[4], ls = 0.f;
#pragma unroll
      for (int jt = 0; jt < 4; ++jt) { p[jt] = exp2f(sv[jt] - mnew); ls += p[jt]; }
      ls = rsum16(ls);
      lrow[m] = lrow[m] * alpha + ls;
      mrow[m] = mnew;
#pragma unroll
      for (int dt = 0; dt < 4; ++dt) of[dt][m] *= alpha;
#pragma unroll
      for (int jt = 0; jt < 4; ++jt) {
        const int col = (jt << 4) + l15;
        const int ch = col >> 3;
        Ps[(irow << 6) + ((ch ^ (irow & 7)) << 3) + (col & 7)] = f2bf(p[jt]);
      }
    }

    // ---- band MFMA for block tt+2 (after ring reads; barrier-separated use)
    BAND_MFMA(tt + 2);

    // ---- PV: O += P @ V  (A = P own rows, B = Vt)
    __builtin_amdgcn_s_setprio(1);
#pragma unroll
    for (int kk = 0; kk < 2; ++kk) {
      const int cb = l4 + (kk << 2);
      const int pr = rb_ + l15;
      const s16x8 pf = *(const s16x8*)&Ps[(pr << 6) + ((cb ^ (pr & 7)) << 3)];
#pragma unroll
      for (int dt = 0; dt < 4; ++dt) {
        const int dr = (dt << 4) + l15;
        const int slot = cb ^ (dr & 7) ^ ((dt << 1) + (l15 >> 3));
        const s16x8 vf = *(const s16x8*)&Vt[(dr << 6) + (slot << 3)];
        of[dt] = __builtin_amdgcn_mfma_f32_16x16x32_bf16(pf, vf, of[dt], 0, 0, 0);
      }
    }
    __builtin_amdgcn_s_setprio(0);
  }

  // ---- epilogue: normalized output, single bf16, [B,S,E] at e=h*64+d
#pragma unroll
  for (int m = 0; m < 4; ++m) {
    const float inv = 1.f / lrow[m];
    const int srow = s0 + rb_ + (l4 << 2) + m;
    const size_t off0 = ((size_t)bb * S_LEN + srow) * E_DIM + (hh << 6) + l15;
#pragma unroll
    for (int dt = 0; dt < 4; ++dt)
      AO[off0 + (dt << 4)] = f2bf(of[dt][m] * inv);
  }
#undef BAND_MFMA
}

// ---------------------------------------------------------------------------
extern "C" void kernel_launch(void* const* d_in, const int* in_sizes, int n_in,
                              void* d_out, int out_size, void* d_ws, size_t ws_size,
                              hipStream_t stream) {
  (void)in_sizes; (void)n_in; (void)out_size; (void)ws_size;
  const float* query = (const float*)d_in[0];
  const float* key   = (const float*)d_in[1];
  const float* value = (const float*)d_in[2];
  const float* Wq = (const float*)d_in[3];
  const float* bq = (const float*)d_in[4];
  const float* Wk = (const float*)d_in[5];
  const float* bk = (const float*)d_in[6];
  const float* Wv = (const float*)d_in[7];
  const float* bv = (const float*)d_in[8];
  const float* Wo = (const float*)d_in[9];
  const float* bo = (const float*)d_in[10];
  const float* tbl = (const float*)d_in[11];

  const size_t per = (size_t)B_SZ * H_NUM * S_LEN * HD;   // 4,194,304 elems
  const size_t wsz = (size_t)E_DIM * E_DIM;               // 1,048,576 elems
  unsigned short* p = (unsigned short*)d_ws;
  unsigned short* wsQb = p; p += per;
  unsigned short* wsKb = p; p += per;
  unsigned short* wsVb = p; p += per;
  unsigned short* wsRb = p; p += 131072;
  unsigned short* wsXq = p; p += per;
  unsigned short* wsXk = p; p += per;
  unsigned short* wsXv = p; p += per;
  unsigned short* wsWq = p; p += wsz;
  unsigned short* wsWk = p; p += wsz;
  unsigned short* wsWv = p; p += wsz;
  unsigned short* wsWo = p; p += wsz;
  unsigned short* wsA  = p; p += per;      // attn out bf16
  float* out = (float*)d_out;

  dim3 blk(256);
  hipLaunchKernelGGL(conv_all, dim3(8256), blk, 0, stream,
                     query, key, value, Wq, Wk, Wv, Wo, tbl,
                     wsXq, wsXk, wsXv, wsWq, wsWk, wsWv, wsWo, wsRb);
  hipLaunchKernelGGL(qkv_mfma, dim3(32, 8, 3), blk, 0, stream,
                     wsXq, wsXk, wsXv, wsWq, wsWk, wsWv, bq, bk, bv,
                     wsQb, wsKb, wsVb);
  hipLaunchKernelGGL(attn_mfma, dim3(1024), blk, 0, stream,
                     wsQb, wsKb, wsVb, wsRb, wsA);
  hipLaunchKernelGGL(outp_mfma, dim3(32, 8), blk, 0, stream,
                     wsA, wsWo, bo, out);
}

// Round 14
// 161.380 us; speedup vs baseline: 1.0103x; 1.0103x over previous
//
#include <hip/hip_runtime.h>
#include <math.h>

#define S_LEN 1024
#define B_SZ 4
#define E_DIM 1024
#define H_NUM 16
#define HD 64
#define IDX_MAX 2044   // clip(dist,-1022,1022)+1022 in [0,2044]
#define NEG_BIG (-3.0e38f)

typedef __attribute__((ext_vector_type(8))) short s16x8;   // 8 bf16 (4 VGPRs)
typedef __attribute__((ext_vector_type(4))) float f32x4;

__device__ __forceinline__ unsigned short f2bf(float f) {
  union { float f; unsigned int u; } v; v.f = f;
  return (unsigned short)((v.u + 0x7FFFu + ((v.u >> 16) & 1u)) >> 16);  // RNE
}
__device__ __forceinline__ float bf2f(unsigned short h) {
  union { unsigned int u; float f; } v; v.u = ((unsigned int)h) << 16;
  return v.f;
}
__device__ __forceinline__ void gload16(const void* g, void* l) {
  __builtin_amdgcn_global_load_lds(
      (const __attribute__((address_space(1))) void*)g,
      (__attribute__((address_space(3))) void*)l, 16, 0, 0);
}
__device__ __forceinline__ int clampg(int g) {
  return g < 0 ? 0 : (g > IDX_MAX ? IDX_MAX : g);
}

// ---- DPP 16-lane rotation butterfly reduces (VALU pipe, not LDS) ----------
template <int CTRL>
__device__ __forceinline__ float dppror(float x) {
  union { float f; int i; } a, b;
  a.f = x;
  b.i = __builtin_amdgcn_update_dpp(a.i, a.i, CTRL, 0xF, 0xF, false);
  return b.f;
}
__device__ __forceinline__ float rmax16(float x) {
  x = fmaxf(x, dppror<0x128>(x));
  x = fmaxf(x, dppror<0x124>(x));
  x = fmaxf(x, dppror<0x122>(x));
  x = fmaxf(x, dppror<0x121>(x));
  return x;
}
__device__ __forceinline__ float rsum16(float x) {
  x += dppror<0x128>(x);
  x += dppror<0x124>(x);
  x += dppror<0x122>(x);
  x += dppror<0x121>(x);
  return x;
}

// ---------------------------------------------------------------------------
// All fp32->bf16 conversions in one launch (8 segments).  [validated R4-R13]
// ---------------------------------------------------------------------------
__global__ __launch_bounds__(256) void conv_all(
    const float* __restrict__ q, const float* __restrict__ k,
    const float* __restrict__ v, const float* __restrict__ wq,
    const float* __restrict__ wk, const float* __restrict__ wv,
    const float* __restrict__ wo, const float* __restrict__ tb,
    unsigned short* __restrict__ oq, unsigned short* __restrict__ ok,
    unsigned short* __restrict__ ov, unsigned short* __restrict__ owq,
    unsigned short* __restrict__ owk, unsigned short* __restrict__ owv,
    unsigned short* __restrict__ owo, unsigned short* __restrict__ otb)
{
  const int b = blockIdx.x;
  const float* src; unsigned short* dst; int n, lb;
  if (b < 2048)      { src = q;  dst = oq;  n = 4194304; lb = b; }
  else if (b < 4096) { src = k;  dst = ok;  n = 4194304; lb = b - 2048; }
  else if (b < 6144) { src = v;  dst = ov;  n = 4194304; lb = b - 4096; }
  else if (b < 6656) { src = wq; dst = owq; n = 1048576; lb = b - 6144; }
  else if (b < 7168) { src = wk; dst = owk; n = 1048576; lb = b - 6656; }
  else if (b < 7680) { src = wv; dst = owv; n = 1048576; lb = b - 7168; }
  else if (b < 8192) { src = wo; dst = owo; n = 1048576; lb = b - 7680; }
  else               { src = tb; dst = otb; n = 131008;  lb = b - 8192; }
  const int i = (lb * 256 + threadIdx.x) << 3;
  if (i >= n) return;
  const float4 a = *(const float4*)(src + i);
  const float4 c = *(const float4*)(src + i + 4);
  union { unsigned short us[8]; uint4 v4; } u;
  u.us[0] = f2bf(a.x); u.us[1] = f2bf(a.y); u.us[2] = f2bf(a.z); u.us[3] = f2bf(a.w);
  u.us[4] = f2bf(c.x); u.us[5] = f2bf(c.y); u.us[6] = f2bf(c.z); u.us[7] = f2bf(c.w);
  *(uint4*)(dst + i) = u.v4;
}

// ---------------------------------------------------------------------------
// Fused QKV projection [validated R3-R13]: bf16 MFMA, 128x128 tile, BK=64.
// q-scale folds log2(e) (softmax runs in exp2 domain).
// ---------------------------------------------------------------------------
__global__ __launch_bounds__(256, 3) void qkv_mfma(
    const unsigned short* __restrict__ X0, const unsigned short* __restrict__ X1,
    const unsigned short* __restrict__ X2,
    const unsigned short* __restrict__ W0, const unsigned short* __restrict__ W1,
    const unsigned short* __restrict__ W2,
    const float* __restrict__ bp0, const float* __restrict__ bp1,
    const float* __restrict__ bp2,
    unsigned short* __restrict__ O0, unsigned short* __restrict__ O1,
    unsigned short* __restrict__ O2)
{
  __shared__ unsigned short As[128 * 64];
  __shared__ unsigned short Bs[128 * 64];

  const int z = blockIdx.z;
  const unsigned short* X = z == 0 ? X0 : (z == 1 ? X1 : X2);
  const unsigned short* W = z == 0 ? W0 : (z == 1 ? W1 : W2);
  const float* bias = z == 0 ? bp0 : (z == 1 ? bp1 : bp2);
  unsigned short* O = z == 0 ? O0 : (z == 1 ? O1 : O2);
  const float scale = z == 0 ? 0.18033688f : 1.0f;   // 0.125 * log2(e)

  const int tid = threadIdx.x;
  const int w = tid >> 6, l = tid & 63;
  const int l15 = l & 15, l4 = l >> 4;
  const int m0 = blockIdx.x << 7, n0 = blockIdx.y << 7;
  const int wr0 = (w >> 1) << 6, wc0 = (w & 1) << 6;

  f32x4 acc[4][4];
#pragma unroll
  for (int mt = 0; mt < 4; ++mt)
#pragma unroll
    for (int nt = 0; nt < 4; ++nt) acc[mt][nt] = (f32x4){0.f, 0.f, 0.f, 0.f};

  float bias4[4];
#pragma unroll
  for (int nt = 0; nt < 4; ++nt) bias4[nt] = bias[n0 + wc0 + (nt << 4) + l15];

  const int cbase = (w << 6) + l;

  for (int kt = 0; kt < 16; ++kt) {
    const int k0 = kt << 6;
    __syncthreads();
#pragma unroll
    for (int i = 0; i < 4; ++i) {
      const int c = cbase + (i << 8);
      const int r = c >> 3, kc = c & 7;
      char* ldsA = (char*)As + (((i << 2) + w) << 10);
      char* ldsB = (char*)Bs + (((i << 2) + w) << 10);
      gload16(X + (size_t)(m0 + r) * E_DIM + k0 + (kc << 3), ldsA);
      gload16(W + (size_t)(n0 + r) * E_DIM + k0 + (kc << 3), ldsB);
    }
    __syncthreads();
#pragma unroll
    for (int kh = 0; kh < 2; ++kh) {
      s16x8 af[4], bfr[4];
#pragma unroll
      for (int mt = 0; mt < 4; ++mt)
        af[mt] = *(const s16x8*)&As[(wr0 + (mt << 4) + l15) * 64 + (kh << 5) + (l4 << 3)];
#pragma unroll
      for (int nt = 0; nt < 4; ++nt)
        bfr[nt] = *(const s16x8*)&Bs[(wc0 + (nt << 4) + l15) * 64 + (kh << 5) + (l4 << 3)];
#pragma unroll
      for (int mt = 0; mt < 4; ++mt)
#pragma unroll
        for (int nt = 0; nt < 4; ++nt)
          acc[mt][nt] = __builtin_amdgcn_mfma_f32_16x16x32_bf16(
              af[mt], bfr[nt], acc[mt][nt], 0, 0, 0);
    }
  }

#pragma unroll
  for (int mt = 0; mt < 4; ++mt)
#pragma unroll
    for (int nt = 0; nt < 4; ++nt) {
      const int n = n0 + wc0 + (nt << 4) + l15;
      const int h = n >> 6, d = n & 63;
      const f32x4 c = acc[mt][nt];
#pragma unroll
      for (int r = 0; r < 4; ++r) {
        const int m = m0 + wr0 + (mt << 4) + (l4 << 2) + r;
        const int s = m >> 2, b = m & 3;
        O[((((size_t)b * H_NUM + h) * S_LEN) + s) * HD + d] =
            f2bf((c[r] + bias4[nt]) * scale);
      }
    }
}

// ---------------------------------------------------------------------------
// Output projection, single bf16 A [validated R10-R13].
// ---------------------------------------------------------------------------
__global__ __launch_bounds__(256) void outp_mfma(
    const unsigned short* __restrict__ A, const unsigned short* __restrict__ W,
    const float* __restrict__ bias, float* __restrict__ out)
{
  __shared__ unsigned short As[128 * 64];
  __shared__ unsigned short Bs[128 * 64];

  const int tid = threadIdx.x;
  const int w = tid >> 6, l = tid & 63;
  const int l15 = l & 15, l4 = l >> 4;
  const int m0 = blockIdx.x << 7, n0 = blockIdx.y << 7;
  const int wr0 = (w >> 1) << 6, wc0 = (w & 1) << 6;

  f32x4 acc[4][4];
#pragma unroll
  for (int mt = 0; mt < 4; ++mt)
#pragma unroll
    for (int nt = 0; nt < 4; ++nt) acc[mt][nt] = (f32x4){0.f, 0.f, 0.f, 0.f};

  float bias4[4];
#pragma unroll
  for (int nt = 0; nt < 4; ++nt) bias4[nt] = bias[n0 + wc0 + (nt << 4) + l15];

  const int cbase = (w << 6) + l;

  for (int kt = 0; kt < 16; ++kt) {
    const int k0 = kt << 6;
    __syncthreads();
#pragma unroll
    for (int i = 0; i < 4; ++i) {
      const int c = cbase + (i << 8);
      const int r = c >> 3, kc = c & 7;
      char* ldsA = (char*)As + (((i << 2) + w) << 10);
      char* ldsB = (char*)Bs + (((i << 2) + w) << 10);
      gload16(A + (size_t)(m0 + r) * E_DIM + k0 + (kc << 3), ldsA);
      gload16(W + (size_t)(n0 + r) * E_DIM + k0 + (kc << 3), ldsB);
    }
    __syncthreads();
#pragma unroll
    for (int kh = 0; kh < 2; ++kh) {
      s16x8 af[4], bfr[4];
      const int ko = (kh << 5) + (l4 << 3);
#pragma unroll
      for (int mt = 0; mt < 4; ++mt)
        af[mt] = *(const s16x8*)&As[(wr0 + (mt << 4) + l15) * 64 + ko];
#pragma unroll
      for (int nt = 0; nt < 4; ++nt)
        bfr[nt] = *(const s16x8*)&Bs[(wc0 + (nt << 4) + l15) * 64 + ko];
#pragma unroll
      for (int mt = 0; mt < 4; ++mt)
#pragma unroll
        for (int nt = 0; nt < 4; ++nt)
          acc[mt][nt] = __builtin_amdgcn_mfma_f32_16x16x32_bf16(
              af[mt], bfr[nt], acc[mt][nt], 0, 0, 0);
    }
  }

#pragma unroll
  for (int mt = 0; mt < 4; ++mt)
#pragma unroll
    for (int nt = 0; nt < 4; ++nt) {
      const int n = n0 + wc0 + (nt << 4) + l15;
      const f32x4 c = acc[mt][nt];
#pragma unroll
      for (int r = 0; r < 4; ++r) {
        const int m = m0 + wr0 + (mt << 4) + (l4 << 2) + r;
        const int b = m >> 10, s = m & 1023;
        out[((size_t)s * B_SZ + b) * E_DIM + n] = c[r] + bias4[nt];
      }
    }
}

// ---------------------------------------------------------------------------
// bf16 MFMA flash attention — R10's validated structure (i-major fp32 band
// ring, scalar gather; T14 prefetch; DPP reduces; T5 setprio; XCD swizzle)
// with R12's validated exp2-domain softmax kept (q-scale carries log2e).
// R11-R13 ring variants all regressed; this is the best-known configuration.
// ---------------------------------------------------------------------------
__global__ __launch_bounds__(256) void attn_mfma(
    const unsigned short* __restrict__ Qb, const unsigned short* __restrict__ Kb,
    const unsigned short* __restrict__ Vb, const unsigned short* __restrict__ Rb,
    unsigned short* __restrict__ AO)
{
  __shared__ unsigned short Ks[64 * 64];   // [j][d], slot = cb ^ (r&7)
  __shared__ unsigned short Rs[64 * 64];   // [r][d], slot = cb ^ (r&7)
  __shared__ unsigned short Vt[64 * 64];   // [d][j], slot = cb ^ (d&7) ^ ((d>>3)&7)
  __shared__ unsigned short Ps[64 * 64];   // [i][j], slot = cb ^ (i&7)
  __shared__ float band[64 * 132];         // ring: row i, slot 0..127

  const int tid = threadIdx.x;
  const int lane = tid & 63;
  const int w = tid >> 6;
  // XCD swizzle: all 16 s-blocks of a bh share bh%8's XCD (L2 locality).
  const int x = blockIdx.x;
  const int idx = x >> 3;
  const int bh = (x & 7) + ((idx & 7) << 3);   // 0..63
  const int st = idx >> 3;                     // 0..15
  const int s0 = st << 6;
  const int bb = bh >> 4, hh = bh & 15;
  const size_t base = (size_t)bh * (S_LEN * HD);
  const int l15 = lane & 15, l4 = lane >> 4;
  const int rb_ = w << 4;                 // wave's q-row base

  // staging maps
  const int sr = tid >> 3, scb = tid & 7;          // K/R rows, chunk
  const int ksl = (scb ^ (sr & 7)) << 3;           // swizzled chunk slot
  const int jp = tid >> 3, vc = tid & 7;           // V: j-pair, d-chunk
  const int jc = jp >> 2, jlow = (jp & 3) << 1;

  const int rbase = 959 - s0;

  // Q fragments (A-operand: row=lane&15, k=(lane>>4)*8+e)
  s16x8 qf0, qf1;
  {
    const unsigned short* qp =
        Qb + base + (size_t)(s0 + rb_ + l15) * HD + (l4 << 3);
    qf0 = *(const s16x8*)(qp);
    qf1 = *(const s16x8*)(qp + 32);
  }

  f32x4 of[4];
  float mrow[4], lrow[4];
#pragma unroll
  for (int m = 0; m < 4; ++m) {
    of[m] = (f32x4){0.f, 0.f, 0.f, 0.f};
    mrow[m] = NEG_BIG; lrow[m] = 0.f;
  }

  // band MFMA + ring write for the block currently staged in Rs
#define BAND_MFMA(H0)                                                          \
  {                                                                            \
    f32x4 bq[4];                                                               \
    _Pragma("unroll") for (int rt = 0; rt < 4; ++rt)                           \
        bq[rt] = (f32x4){0.f, 0.f, 0.f, 0.f};                                  \
    __builtin_amdgcn_s_setprio(1);                                             \
    _Pragma("unroll") for (int kk = 0; kk < 2; ++kk) {                         \
      const s16x8 qv = kk ? qf1 : qf0;                                         \
      const int cb = l4 + (kk << 2);                                           \
      _Pragma("unroll") for (int rt = 0; rt < 4; ++rt) {                       \
        const int r = (rt << 4) + l15;                                         \
        const s16x8 rf = *(const s16x8*)&Rs[(r << 6) + ((cb ^ (r & 7)) << 3)]; \
        bq[rt] = __builtin_amdgcn_mfma_f32_16x16x32_bf16(qv, rf, bq[rt], 0, 0, 0); \
      }                                                                        \
    }                                                                          \
    __builtin_amdgcn_s_setprio(0);                                             \
    _Pragma("unroll") for (int rt = 0; rt < 4; ++rt)                           \
      _Pragma("unroll") for (int m = 0; m < 4; ++m)                            \
        band[(rb_ + (l4 << 2) + m) * 132 + (H0) + (rt << 4) + l15] = bq[rt][m];\
  }

  // ---- prologue: band blocks 0 and 1
  s16x8 Kr0, Kr1, Vr0, Vr1, Rr0, Rr1;
  {
    s16x8 tA0, tA1, tB0, tB1;
    tA0 = *(const s16x8*)(Rb + (size_t)clampg(rbase + sr) * HD + (scb << 3));
    tA1 = *(const s16x8*)(Rb + (size_t)clampg(rbase + 32 + sr) * HD + (scb << 3));
    tB0 = *(const s16x8*)(Rb + (size_t)clampg(rbase + 64 + sr) * HD + (scb << 3));
    tB1 = *(const s16x8*)(Rb + (size_t)clampg(rbase + 96 + sr) * HD + (scb << 3));
    *(s16x8*)&Rs[(sr << 6) + ksl] = tA0;
    *(s16x8*)&Rs[((sr + 32) << 6) + ksl] = tA1;
    __syncthreads();
    BAND_MFMA(0);
    // prefetch tile 0 K,V and R block 2
    Kr0 = *(const s16x8*)(Kb + base + (size_t)sr * HD + (scb << 3));
    Kr1 = *(const s16x8*)(Kb + base + (size_t)(32 + sr) * HD + (scb << 3));
    Vr0 = *(const s16x8*)(Vb + base + (size_t)(jp << 1) * HD + (vc << 3));
    Vr1 = *(const s16x8*)(Vb + base + (size_t)((jp << 1) + 1) * HD + (vc << 3));
    Rr0 = *(const s16x8*)(Rb + (size_t)clampg(rbase + 128 + sr) * HD + (scb << 3));
    Rr1 = *(const s16x8*)(Rb + (size_t)clampg(rbase + 160 + sr) * HD + (scb << 3));
    __syncthreads();               // all waves done reading Rs (block 0)
    *(s16x8*)&Rs[(sr << 6) + ksl] = tB0;
    *(s16x8*)&Rs[((sr + 32) << 6) + ksl] = tB1;
    __syncthreads();
    BAND_MFMA(64);
  }

  for (int tt = 0; tt < 16; ++tt) {
    const int t0 = tt << 6;
    __syncthreads();   // previous compute (and prologue BAND(64)) done with LDS

    // ---- stage prefetched regs -> LDS
    *(s16x8*)&Ks[(sr << 6) + ksl] = Kr0;
    *(s16x8*)&Ks[((sr + 32) << 6) + ksl] = Kr1;
    *(s16x8*)&Rs[(sr << 6) + ksl] = Rr0;
    *(s16x8*)&Rs[((sr + 32) << 6) + ksl] = Rr1;
#pragma unroll
    for (int e = 0; e < 8; ++e) {
      const int d = (vc << 3) + e;
      const int slot = jc ^ e ^ vc;
      const unsigned int pack = (unsigned int)(unsigned short)Vr0[e] |
                                ((unsigned int)(unsigned short)Vr1[e] << 16);
      *(unsigned int*)&Vt[(d << 6) + (slot << 3) + jlow] = pack;
    }
    __syncthreads();

    // ---- prefetch next tile (K,V) and R block tt+3
    if (tt < 15) {
      const int tn = t0 + 64;
      Kr0 = *(const s16x8*)(Kb + base + (size_t)(tn + sr) * HD + (scb << 3));
      Kr1 = *(const s16x8*)(Kb + base + (size_t)(tn + 32 + sr) * HD + (scb << 3));
      Vr0 = *(const s16x8*)(Vb + base + (size_t)(tn + (jp << 1)) * HD + (vc << 3));
      Vr1 = *(const s16x8*)(Vb + base + (size_t)(tn + (jp << 1) + 1) * HD + (vc << 3));
      const int gb = rbase + ((tt + 3) << 6) + sr;
      Rr0 = *(const s16x8*)(Rb + (size_t)clampg(gb) * HD + (scb << 3));
      Rr1 = *(const s16x8*)(Rb + (size_t)clampg(gb + 32) * HD + (scb << 3));
    }

    // ---- content MFMA
    f32x4 cf[4];
#pragma unroll
    for (int jt = 0; jt < 4; ++jt) cf[jt] = (f32x4){0.f, 0.f, 0.f, 0.f};
    __builtin_amdgcn_s_setprio(1);
#pragma unroll
    for (int kk = 0; kk < 2; ++kk) {
      const s16x8 qv = kk ? qf1 : qf0;
      const int cb = l4 + (kk << 2);
#pragma unroll
      for (int jt = 0; jt < 4; ++jt) {
        const int r = (jt << 4) + l15;
        const s16x8 kf = *(const s16x8*)&Ks[(r << 6) + ((cb ^ (r & 7)) << 3)];
        cf[jt] = __builtin_amdgcn_mfma_f32_16x16x32_bf16(qv, kf, cf[jt], 0, 0, 0);
      }
    }
    __builtin_amdgcn_s_setprio(0);

    // ---- online softmax (exp2 domain) with ring-band gather; P -> LDS
#pragma unroll
    for (int m = 0; m < 4; ++m) {
      const int irow = rb_ + (l4 << 2) + m;
      const int bc = t0 + 63 - irow;
      const float* bp = &band[irow * 132];
      float sv[4];
#pragma unroll
      for (int jt = 0; jt < 4; ++jt)
        sv[jt] = cf[jt][m] + bp[(bc + (jt << 4) + l15) & 127];
      float mx = fmaxf(fmaxf(sv[0], sv[1]), fmaxf(sv[2], sv[3]));
      mx = rmax16(mx);
      const float mnew = fmaxf(mrow[m], mx);
      const float alpha = exp2f(mrow[m] - mnew);
      float p[4], ls = 0.f;
#pragma unroll
      for (int jt = 0; jt < 4; ++jt) { p[jt] = exp2f(sv[jt] - mnew); ls += p[jt]; }
      ls = rsum16(ls);
      lrow[m] = lrow[m] * alpha + ls;
      mrow[m] = mnew;
#pragma unroll
      for (int dt = 0; dt < 4; ++dt) of[dt][m] *= alpha;
#pragma unroll
      for (int jt = 0; jt < 4; ++jt) {
        const int col = (jt << 4) + l15;
        const int ch = col >> 3;
        Ps[(irow << 6) + ((ch ^ (irow & 7)) << 3) + (col & 7)] = f2bf(p[jt]);
      }
    }

    // ---- band MFMA for block tt+2 -> ring half (tt&1)  (wave-private rows)
    BAND_MFMA((tt & 1) << 6);

    // ---- PV: O += P @ V  (A = P own rows, B = Vt)
    __builtin_amdgcn_s_setprio(1);
#pragma unroll
    for (int kk = 0; kk < 2; ++kk) {
      const int cb = l4 + (kk << 2);
      const int pr = rb_ + l15;
      const s16x8 pf = *(const s16x8*)&Ps[(pr << 6) + ((cb ^ (pr & 7)) << 3)];
#pragma unroll
      for (int dt = 0; dt < 4; ++dt) {
        const int dr = (dt << 4) + l15;
        const int slot = cb ^ (dr & 7) ^ ((dt << 1) + (l15 >> 3));
        const s16x8 vf = *(const s16x8*)&Vt[(dr << 6) + (slot << 3)];
        of[dt] = __builtin_amdgcn_mfma_f32_16x16x32_bf16(pf, vf, of[dt], 0, 0, 0);
      }
    }
    __builtin_amdgcn_s_setprio(0);
  }

  // ---- epilogue: normalized output, single bf16, [B,S,E] at e=h*64+d
#pragma unroll
  for (int m = 0; m < 4; ++m) {
    const float inv = 1.f / lrow[m];
    const int srow = s0 + rb_ + (l4 << 2) + m;
    const size_t off0 = ((size_t)bb * S_LEN + srow) * E_DIM + (hh << 6) + l15;
#pragma unroll
    for (int dt = 0; dt < 4; ++dt)
      AO[off0 + (dt << 4)] = f2bf(of[dt][m] * inv);
  }
#undef BAND_MFMA
}

// ---------------------------------------------------------------------------
extern "C" void kernel_launch(void* const* d_in, const int* in_sizes, int n_in,
                              void* d_out, int out_size, void* d_ws, size_t ws_size,
                              hipStream_t stream) {
  (void)in_sizes; (void)n_in; (void)out_size; (void)ws_size;
  const float* query = (const float*)d_in[0];
  const float* key   = (const float*)d_in[1];
  const float* value = (const float*)d_in[2];
  const float* Wq = (const float*)d_in[3];
  const float* bq = (const float*)d_in[4];
  const float* Wk = (const float*)d_in[5];
  const float* bk = (const float*)d_in[6];
  const float* Wv = (const float*)d_in[7];
  const float* bv = (const float*)d_in[8];
  const float* Wo = (const float*)d_in[9];
  const float* bo = (const float*)d_in[10];
  const float* tbl = (const float*)d_in[11];

  const size_t per = (size_t)B_SZ * H_NUM * S_LEN * HD;   // 4,194,304 elems
  const size_t wsz = (size_t)E_DIM * E_DIM;               // 1,048,576 elems
  unsigned short* p = (unsigned short*)d_ws;
  unsigned short* wsQb = p; p += per;
  unsigned short* wsKb = p; p += per;
  unsigned short* wsVb = p; p += per;
  unsigned short* wsRb = p; p += 131072;
  unsigned short* wsXq = p; p += per;
  unsigned short* wsXk = p; p += per;
  unsigned short* wsXv = p; p += per;
  unsigned short* wsWq = p; p += wsz;
  unsigned short* wsWk = p; p += wsz;
  unsigned short* wsWv = p; p += wsz;
  unsigned short* wsWo = p; p += wsz;
  unsigned short* wsA  = p; p += per;      // attn out bf16
  float* out = (float*)d_out;

  dim3 blk(256);
  hipLaunchKernelGGL(conv_all, dim3(8256), blk, 0, stream,
                     query, key, value, Wq, Wk, Wv, Wo, tbl,
                     wsXq, wsXk, wsXv, wsWq, wsWk, wsWv, wsWo, wsRb);
  hipLaunchKernelGGL(qkv_mfma, dim3(32, 8, 3), blk, 0, stream,
                     wsXq, wsXk, wsXv, wsWq, wsWk, wsWv, bq, bk, bv,
                     wsQb, wsKb, wsVb);
  hipLaunchKernelGGL(attn_mfma, dim3(1024), blk, 0, stream,
                     wsQb, wsKb, wsVb, wsRb, wsA);
  hipLaunchKernelGGL(outp_mfma, dim3(32, 8), blk, 0, stream,
                     wsA, wsWo, bo, out);
}

// Round 15
// 152.782 us; speedup vs baseline: 1.0671x; 1.0563x over previous
//
#include <hip/hip_runtime.h>
#include <math.h>

#define S_LEN 1024
#define B_SZ 4
#define E_DIM 1024
#define H_NUM 16
#define HD 64
#define IDX_MAX 2044   // clip(dist,-1022,1022)+1022 in [0,2044]
#define NEG_BIG (-3.0e38f)

typedef __attribute__((ext_vector_type(8))) short s16x8;   // 8 bf16 (4 VGPRs)
typedef __attribute__((ext_vector_type(4))) float f32x4;

__device__ __forceinline__ unsigned short f2bf(float f) {
  union { float f; unsigned int u; } v; v.f = f;
  return (unsigned short)((v.u + 0x7FFFu + ((v.u >> 16) & 1u)) >> 16);  // RNE
}
__device__ __forceinline__ float bf2f(unsigned short h) {
  union { unsigned int u; float f; } v; v.u = ((unsigned int)h) << 16;
  return v.f;
}
__device__ __forceinline__ void gload16(const void* g, void* l) {
  __builtin_amdgcn_global_load_lds(
      (const __attribute__((address_space(1))) void*)g,
      (__attribute__((address_space(3))) void*)l, 16, 0, 0);
}
__device__ __forceinline__ int clampg(int g) {
  return g < 0 ? 0 : (g > IDX_MAX ? IDX_MAX : g);
}
// raw v_exp_f32: D = 2^S0 (single instruction; inputs here are <= 0 finite)
__device__ __forceinline__ float fexp2(float x) {
  return __builtin_amdgcn_exp2f(x);
}

// ---- DPP 16-lane rotation butterfly reduces (VALU pipe, not LDS) ----------
template <int CTRL>
__device__ __forceinline__ float dppror(float x) {
  union { float f; int i; } a, b;
  a.f = x;
  b.i = __builtin_amdgcn_update_dpp(a.i, a.i, CTRL, 0xF, 0xF, false);
  return b.f;
}
__device__ __forceinline__ float rmax16(float x) {
  x = fmaxf(x, dppror<0x128>(x));
  x = fmaxf(x, dppror<0x124>(x));
  x = fmaxf(x, dppror<0x122>(x));
  x = fmaxf(x, dppror<0x121>(x));
  return x;
}
__device__ __forceinline__ float rsum16(float x) {
  x += dppror<0x128>(x);
  x += dppror<0x124>(x);
  x += dppror<0x122>(x);
  x += dppror<0x121>(x);
  return x;
}

// ---------------------------------------------------------------------------
// All fp32->bf16 conversions in one launch (8 segments).  [validated R4-R14]
// ---------------------------------------------------------------------------
__global__ __launch_bounds__(256) void conv_all(
    const float* __restrict__ q, const float* __restrict__ k,
    const float* __restrict__ v, const float* __restrict__ wq,
    const float* __restrict__ wk, const float* __restrict__ wv,
    const float* __restrict__ wo, const float* __restrict__ tb,
    unsigned short* __restrict__ oq, unsigned short* __restrict__ ok,
    unsigned short* __restrict__ ov, unsigned short* __restrict__ owq,
    unsigned short* __restrict__ owk, unsigned short* __restrict__ owv,
    unsigned short* __restrict__ owo, unsigned short* __restrict__ otb)
{
  const int b = blockIdx.x;
  const float* src; unsigned short* dst; int n, lb;
  if (b < 2048)      { src = q;  dst = oq;  n = 4194304; lb = b; }
  else if (b < 4096) { src = k;  dst = ok;  n = 4194304; lb = b - 2048; }
  else if (b < 6144) { src = v;  dst = ov;  n = 4194304; lb = b - 4096; }
  else if (b < 6656) { src = wq; dst = owq; n = 1048576; lb = b - 6144; }
  else if (b < 7168) { src = wk; dst = owk; n = 1048576; lb = b - 6656; }
  else if (b < 7680) { src = wv; dst = owv; n = 1048576; lb = b - 7168; }
  else if (b < 8192) { src = wo; dst = owo; n = 1048576; lb = b - 7680; }
  else               { src = tb; dst = otb; n = 131008;  lb = b - 8192; }
  const int i = (lb * 256 + threadIdx.x) << 3;
  if (i >= n) return;
  const float4 a = *(const float4*)(src + i);
  const float4 c = *(const float4*)(src + i + 4);
  union { unsigned short us[8]; uint4 v4; } u;
  u.us[0] = f2bf(a.x); u.us[1] = f2bf(a.y); u.us[2] = f2bf(a.z); u.us[3] = f2bf(a.w);
  u.us[4] = f2bf(c.x); u.us[5] = f2bf(c.y); u.us[6] = f2bf(c.z); u.us[7] = f2bf(c.w);
  *(uint4*)(dst + i) = u.v4;
}

// ---------------------------------------------------------------------------
// Fused QKV projection [validated R3-R14]: bf16 MFMA, 128x128 tile, BK=64.
// q-scale folds log2(e) (softmax runs in exp2 domain).
// ---------------------------------------------------------------------------
__global__ __launch_bounds__(256, 3) void qkv_mfma(
    const unsigned short* __restrict__ X0, const unsigned short* __restrict__ X1,
    const unsigned short* __restrict__ X2,
    const unsigned short* __restrict__ W0, const unsigned short* __restrict__ W1,
    const unsigned short* __restrict__ W2,
    const float* __restrict__ bp0, const float* __restrict__ bp1,
    const float* __restrict__ bp2,
    unsigned short* __restrict__ O0, unsigned short* __restrict__ O1,
    unsigned short* __restrict__ O2)
{
  __shared__ unsigned short As[128 * 64];
  __shared__ unsigned short Bs[128 * 64];

  const int z = blockIdx.z;
  const unsigned short* X = z == 0 ? X0 : (z == 1 ? X1 : X2);
  const unsigned short* W = z == 0 ? W0 : (z == 1 ? W1 : W2);
  const float* bias = z == 0 ? bp0 : (z == 1 ? bp1 : bp2);
  unsigned short* O = z == 0 ? O0 : (z == 1 ? O1 : O2);
  const float scale = z == 0 ? 0.18033688f : 1.0f;   // 0.125 * log2(e)

  const int tid = threadIdx.x;
  const int w = tid >> 6, l = tid & 63;
  const int l15 = l & 15, l4 = l >> 4;
  const int m0 = blockIdx.x << 7, n0 = blockIdx.y << 7;
  const int wr0 = (w >> 1) << 6, wc0 = (w & 1) << 6;

  f32x4 acc[4][4];
#pragma unroll
  for (int mt = 0; mt < 4; ++mt)
#pragma unroll
    for (int nt = 0; nt < 4; ++nt) acc[mt][nt] = (f32x4){0.f, 0.f, 0.f, 0.f};

  float bias4[4];
#pragma unroll
  for (int nt = 0; nt < 4; ++nt) bias4[nt] = bias[n0 + wc0 + (nt << 4) + l15];

  const int cbase = (w << 6) + l;

  for (int kt = 0; kt < 16; ++kt) {
    const int k0 = kt << 6;
    __syncthreads();
#pragma unroll
    for (int i = 0; i < 4; ++i) {
      const int c = cbase + (i << 8);
      const int r = c >> 3, kc = c & 7;
      char* ldsA = (char*)As + (((i << 2) + w) << 10);
      char* ldsB = (char*)Bs + (((i << 2) + w) << 10);
      gload16(X + (size_t)(m0 + r) * E_DIM + k0 + (kc << 3), ldsA);
      gload16(W + (size_t)(n0 + r) * E_DIM + k0 + (kc << 3), ldsB);
    }
    __syncthreads();
#pragma unroll
    for (int kh = 0; kh < 2; ++kh) {
      s16x8 af[4], bfr[4];
#pragma unroll
      for (int mt = 0; mt < 4; ++mt)
        af[mt] = *(const s16x8*)&As[(wr0 + (mt << 4) + l15) * 64 + (kh << 5) + (l4 << 3)];
#pragma unroll
      for (int nt = 0; nt < 4; ++nt)
        bfr[nt] = *(const s16x8*)&Bs[(wc0 + (nt << 4) + l15) * 64 + (kh << 5) + (l4 << 3)];
#pragma unroll
      for (int mt = 0; mt < 4; ++mt)
#pragma unroll
        for (int nt = 0; nt < 4; ++nt)
          acc[mt][nt] = __builtin_amdgcn_mfma_f32_16x16x32_bf16(
              af[mt], bfr[nt], acc[mt][nt], 0, 0, 0);
    }
  }

#pragma unroll
  for (int mt = 0; mt < 4; ++mt)
#pragma unroll
    for (int nt = 0; nt < 4; ++nt) {
      const int n = n0 + wc0 + (nt << 4) + l15;
      const int h = n >> 6, d = n & 63;
      const f32x4 c = acc[mt][nt];
#pragma unroll
      for (int r = 0; r < 4; ++r) {
        const int m = m0 + wr0 + (mt << 4) + (l4 << 2) + r;
        const int s = m >> 2, b = m & 3;
        O[((((size_t)b * H_NUM + h) * S_LEN) + s) * HD + d] =
            f2bf((c[r] + bias4[nt]) * scale);
      }
    }
}

// ---------------------------------------------------------------------------
// Output projection, single bf16 A [validated R10-R14].
// ---------------------------------------------------------------------------
__global__ __launch_bounds__(256) void outp_mfma(
    const unsigned short* __restrict__ A, const unsigned short* __restrict__ W,
    const float* __restrict__ bias, float* __restrict__ out)
{
  __shared__ unsigned short As[128 * 64];
  __shared__ unsigned short Bs[128 * 64];

  const int tid = threadIdx.x;
  const int w = tid >> 6, l = tid & 63;
  const int l15 = l & 15, l4 = l >> 4;
  const int m0 = blockIdx.x << 7, n0 = blockIdx.y << 7;
  const int wr0 = (w >> 1) << 6, wc0 = (w & 1) << 6;

  f32x4 acc[4][4];
#pragma unroll
  for (int mt = 0; mt < 4; ++mt)
#pragma unroll
    for (int nt = 0; nt < 4; ++nt) acc[mt][nt] = (f32x4){0.f, 0.f, 0.f, 0.f};

  float bias4[4];
#pragma unroll
  for (int nt = 0; nt < 4; ++nt) bias4[nt] = bias[n0 + wc0 + (nt << 4) + l15];

  const int cbase = (w << 6) + l;

  for (int kt = 0; kt < 16; ++kt) {
    const int k0 = kt << 6;
    __syncthreads();
#pragma unroll
    for (int i = 0; i < 4; ++i) {
      const int c = cbase + (i << 8);
      const int r = c >> 3, kc = c & 7;
      char* ldsA = (char*)As + (((i << 2) + w) << 10);
      char* ldsB = (char*)Bs + (((i << 2) + w) << 10);
      gload16(A + (size_t)(m0 + r) * E_DIM + k0 + (kc << 3), ldsA);
      gload16(W + (size_t)(n0 + r) * E_DIM + k0 + (kc << 3), ldsB);
    }
    __syncthreads();
#pragma unroll
    for (int kh = 0; kh < 2; ++kh) {
      s16x8 af[4], bfr[4];
      const int ko = (kh << 5) + (l4 << 3);
#pragma unroll
      for (int mt = 0; mt < 4; ++mt)
        af[mt] = *(const s16x8*)&As[(wr0 + (mt << 4) + l15) * 64 + ko];
#pragma unroll
      for (int nt = 0; nt < 4; ++nt)
        bfr[nt] = *(const s16x8*)&Bs[(wc0 + (nt << 4) + l15) * 64 + ko];
#pragma unroll
      for (int mt = 0; mt < 4; ++mt)
#pragma unroll
        for (int nt = 0; nt < 4; ++nt)
          acc[mt][nt] = __builtin_amdgcn_mfma_f32_16x16x32_bf16(
              af[mt], bfr[nt], acc[mt][nt], 0, 0, 0);
    }
  }

#pragma unroll
  for (int mt = 0; mt < 4; ++mt)
#pragma unroll
    for (int nt = 0; nt < 4; ++nt) {
      const int n = n0 + wc0 + (nt << 4) + l15;
      const f32x4 c = acc[mt][nt];
#pragma unroll
      for (int r = 0; r < 4; ++r) {
        const int m = m0 + wr0 + (mt << 4) + (l4 << 2) + r;
        const int b = m >> 10, s = m & 1023;
        out[((size_t)s * B_SZ + b) * E_DIM + n] = c[r] + bias4[nt];
      }
    }
}

// ---------------------------------------------------------------------------
// bf16 MFMA flash attention — R10's validated structure (i-major fp32 band
// ring, scalar gather; T14 prefetch; DPP reduces; T5 setprio; XCD swizzle).
// R15 delta: softmax exponentials via raw v_exp_f32 (__builtin_amdgcn_exp2f);
// scale carries log2e from qkv. (R14's libm exp2f cost ~8us of fixup VALU.)
// ---------------------------------------------------------------------------
__global__ __launch_bounds__(256) void attn_mfma(
    const unsigned short* __restrict__ Qb, const unsigned short* __restrict__ Kb,
    const unsigned short* __restrict__ Vb, const unsigned short* __restrict__ Rb,
    unsigned short* __restrict__ AO)
{
  __shared__ unsigned short Ks[64 * 64];   // [j][d], slot = cb ^ (r&7)
  __shared__ unsigned short Rs[64 * 64];   // [r][d], slot = cb ^ (r&7)
  __shared__ unsigned short Vt[64 * 64];   // [d][j], slot = cb ^ (d&7) ^ ((d>>3)&7)
  __shared__ unsigned short Ps[64 * 64];   // [i][j], slot = cb ^ (i&7)
  __shared__ float band[64 * 132];         // ring: row i, slot 0..127

  const int tid = threadIdx.x;
  const int lane = tid & 63;
  const int w = tid >> 6;
  // XCD swizzle: all 16 s-blocks of a bh share bh%8's XCD (L2 locality).
  const int x = blockIdx.x;
  const int idx = x >> 3;
  const int bh = (x & 7) + ((idx & 7) << 3);   // 0..63
  const int st = idx >> 3;                     // 0..15
  const int s0 = st << 6;
  const int bb = bh >> 4, hh = bh & 15;
  const size_t base = (size_t)bh * (S_LEN * HD);
  const int l15 = lane & 15, l4 = lane >> 4;
  const int rb_ = w << 4;                 // wave's q-row base

  // staging maps
  const int sr = tid >> 3, scb = tid & 7;          // K/R rows, chunk
  const int ksl = (scb ^ (sr & 7)) << 3;           // swizzled chunk slot
  const int jp = tid >> 3, vc = tid & 7;           // V: j-pair, d-chunk
  const int jc = jp >> 2, jlow = (jp & 3) << 1;

  const int rbase = 959 - s0;

  // Q fragments (A-operand: row=lane&15, k=(lane>>4)*8+e)
  s16x8 qf0, qf1;
  {
    const unsigned short* qp =
        Qb + base + (size_t)(s0 + rb_ + l15) * HD + (l4 << 3);
    qf0 = *(const s16x8*)(qp);
    qf1 = *(const s16x8*)(qp + 32);
  }

  f32x4 of[4];
  float mrow[4], lrow[4];
#pragma unroll
  for (int m = 0; m < 4; ++m) {
    of[m] = (f32x4){0.f, 0.f, 0.f, 0.f};
    mrow[m] = NEG_BIG; lrow[m] = 0.f;
  }

  // band MFMA + ring write for the block currently staged in Rs
#define BAND_MFMA(H0)                                                          \
  {                                                                            \
    f32x4 bq[4];                                                               \
    _Pragma("unroll") for (int rt = 0; rt < 4; ++rt)                           \
        bq[rt] = (f32x4){0.f, 0.f, 0.f, 0.f};                                  \
    __builtin_amdgcn_s_setprio(1);                                             \
    _Pragma("unroll") for (int kk = 0; kk < 2; ++kk) {                         \
      const s16x8 qv = kk ? qf1 : qf0;                                         \
      const int cb = l4 + (kk << 2);                                           \
      _Pragma("unroll") for (int rt = 0; rt < 4; ++rt) {                       \
        const int r = (rt << 4) + l15;                                         \
        const s16x8 rf = *(const s16x8*)&Rs[(r << 6) + ((cb ^ (r & 7)) << 3)]; \
        bq[rt] = __builtin_amdgcn_mfma_f32_16x16x32_bf16(qv, rf, bq[rt], 0, 0, 0); \
      }                                                                        \
    }                                                                          \
    __builtin_amdgcn_s_setprio(0);                                             \
    _Pragma("unroll") for (int rt = 0; rt < 4; ++rt)                           \
      _Pragma("unroll") for (int m = 0; m < 4; ++m)                            \
        band[(rb_ + (l4 << 2) + m) * 132 + (H0) + (rt << 4) + l15] = bq[rt][m];\
  }

  // ---- prologue: band blocks 0 and 1
  s16x8 Kr0, Kr1, Vr0, Vr1, Rr0, Rr1;
  {
    s16x8 tA0, tA1, tB0, tB1;
    tA0 = *(const s16x8*)(Rb + (size_t)clampg(rbase + sr) * HD + (scb << 3));
    tA1 = *(const s16x8*)(Rb + (size_t)clampg(rbase + 32 + sr) * HD + (scb << 3));
    tB0 = *(const s16x8*)(Rb + (size_t)clampg(rbase + 64 + sr) * HD + (scb << 3));
    tB1 = *(const s16x8*)(Rb + (size_t)clampg(rbase + 96 + sr) * HD + (scb << 3));
    *(s16x8*)&Rs[(sr << 6) + ksl] = tA0;
    *(s16x8*)&Rs[((sr + 32) << 6) + ksl] = tA1;
    __syncthreads();
    BAND_MFMA(0);
    // prefetch tile 0 K,V and R block 2
    Kr0 = *(const s16x8*)(Kb + base + (size_t)sr * HD + (scb << 3));
    Kr1 = *(const s16x8*)(Kb + base + (size_t)(32 + sr) * HD + (scb << 3));
    Vr0 = *(const s16x8*)(Vb + base + (size_t)(jp << 1) * HD + (vc << 3));
    Vr1 = *(const s16x8*)(Vb + base + (size_t)((jp << 1) + 1) * HD + (vc << 3));
    Rr0 = *(const s16x8*)(Rb + (size_t)clampg(rbase + 128 + sr) * HD + (scb << 3));
    Rr1 = *(const s16x8*)(Rb + (size_t)clampg(rbase + 160 + sr) * HD + (scb << 3));
    __syncthreads();               // all waves done reading Rs (block 0)
    *(s16x8*)&Rs[(sr << 6) + ksl] = tB0;
    *(s16x8*)&Rs[((sr + 32) << 6) + ksl] = tB1;
    __syncthreads();
    BAND_MFMA(64);
  }

  for (int tt = 0; tt < 16; ++tt) {
    const int t0 = tt << 6;
    __syncthreads();   // previous compute (and prologue BAND(64)) done with LDS

    // ---- stage prefetched regs -> LDS
    *(s16x8*)&Ks[(sr << 6) + ksl] = Kr0;
    *(s16x8*)&Ks[((sr + 32) << 6) + ksl] = Kr1;
    *(s16x8*)&Rs[(sr << 6) + ksl] = Rr0;
    *(s16x8*)&Rs[((sr + 32) << 6) + ksl] = Rr1;
#pragma unroll
    for (int e = 0; e < 8; ++e) {
      const int d = (vc << 3) + e;
      const int slot = jc ^ e ^ vc;
      const unsigned int pack = (unsigned int)(unsigned short)Vr0[e] |
                                ((unsigned int)(unsigned short)Vr1[e] << 16);
      *(unsigned int*)&Vt[(d << 6) + (slot << 3) + jlow] = pack;
    }
    __syncthreads();

    // ---- prefetch next tile (K,V) and R block tt+3
    if (tt < 15) {
      const int tn = t0 + 64;
      Kr0 = *(const s16x8*)(Kb + base + (size_t)(tn + sr) * HD + (scb << 3));
      Kr1 = *(const s16x8*)(Kb + base + (size_t)(tn + 32 + sr) * HD + (scb << 3));
      Vr0 = *(const s16x8*)(Vb + base + (size_t)(tn + (jp << 1)) * HD + (vc << 3));
      Vr1 = *(const s16x8*)(Vb + base + (size_t)(tn + (jp << 1) + 1) * HD + (vc << 3));
      const int gb = rbase + ((tt + 3) << 6) + sr;
      Rr0 = *(const s16x8*)(Rb + (size_t)clampg(gb) * HD + (scb << 3));
      Rr1 = *(const s16x8*)(Rb + (size_t)clampg(gb + 32) * HD + (scb << 3));
    }

    // ---- content MFMA
    f32x4 cf[4];
#pragma unroll
    for (int jt = 0; jt < 4; ++jt) cf[jt] = (f32x4){0.f, 0.f, 0.f, 0.f};
    __builtin_amdgcn_s_setprio(1);
#pragma unroll
    for (int kk = 0; kk < 2; ++kk) {
      const s16x8 qv = kk ? qf1 : qf0;
      const int cb = l4 + (kk << 2);
#pragma unroll
      for (int jt = 0; jt < 4; ++jt) {
        const int r = (jt << 4) + l15;
        const s16x8 kf = *(const s16x8*)&Ks[(r << 6) + ((cb ^ (r & 7)) << 3)];
        cf[jt] = __builtin_amdgcn_mfma_f32_16x16x32_bf16(qv, kf, cf[jt], 0, 0, 0);
      }
    }
    __builtin_amdgcn_s_setprio(0);

    // ---- online softmax (v_exp_f32 domain) with ring-band gather; P -> LDS
#pragma unroll
    for (int m = 0; m < 4; ++m) {
      const int irow = rb_ + (l4 << 2) + m;
      const int bc = t0 + 63 - irow;
      const float* bp = &band[irow * 132];
      float sv[4];
#pragma unroll
      for (int jt = 0; jt < 4; ++jt)
        sv[jt] = cf[jt][m] + bp[(bc + (jt << 4) + l15) & 127];
      float mx = fmaxf(fmaxf(sv[0], sv[1]), fmaxf(sv[2], sv[3]));
      mx = rmax16(mx);
      const float mnew = fmaxf(mrow[m], mx);
      const float alpha = fexp2(mrow[m] - mnew);
      float p[4], ls = 0.f;
#pragma unroll
      for (int jt = 0; jt < 4; ++jt) { p[jt] = fexp2(sv[jt] - mnew); ls += p[jt]; }
      ls = rsum16(ls);
      lrow[m] = lrow[m] * alpha + ls;
      mrow[m] = mnew;
#pragma unroll
      for (int dt = 0; dt < 4; ++dt) of[dt][m] *= alpha;
#pragma unroll
      for (int jt = 0; jt < 4; ++jt) {
        const int col = (jt << 4) + l15;
        const int ch = col >> 3;
        Ps[(irow << 6) + ((ch ^ (irow & 7)) << 3) + (col & 7)] = f2bf(p[jt]);
      }
    }

    // ---- band MFMA for block tt+2 -> ring half (tt&1)  (wave-private rows)
    BAND_MFMA((tt & 1) << 6);

    // ---- PV: O += P @ V  (A = P own rows, B = Vt)
    __builtin_amdgcn_s_setprio(1);
#pragma unroll
    for (int kk = 0; kk < 2; ++kk) {
      const int cb = l4 + (kk << 2);
      const int pr = rb_ + l15;
      const s16x8 pf = *(const s16x8*)&Ps[(pr << 6) + ((cb ^ (pr & 7)) << 3)];
#pragma unroll
      for (int dt = 0; dt < 4; ++dt) {
        const int dr = (dt << 4) + l15;
        const int slot = cb ^ (dr & 7) ^ ((dt << 1) + (l15 >> 3));
        const s16x8 vf = *(const s16x8*)&Vt[(dr << 6) + (slot << 3)];
        of[dt] = __builtin_amdgcn_mfma_f32_16x16x32_bf16(pf, vf, of[dt], 0, 0, 0);
      }
    }
    __builtin_amdgcn_s_setprio(0);
  }

  // ---- epilogue: normalized output, single bf16, [B,S,E] at e=h*64+d
#pragma unroll
  for (int m = 0; m < 4; ++m) {
    const float inv = 1.f / lrow[m];
    const int srow = s0 + rb_ + (l4 << 2) + m;
    const size_t off0 = ((size_t)bb * S_LEN + srow) * E_DIM + (hh << 6) + l15;
#pragma unroll
    for (int dt = 0; dt < 4; ++dt)
      AO[off0 + (dt << 4)] = f2bf(of[dt][m] * inv);
  }
#undef BAND_MFMA
}

// ---------------------------------------------------------------------------
extern "C" void kernel_launch(void* const* d_in, const int* in_sizes, int n_in,
                              void* d_out, int out_size, void* d_ws, size_t ws_size,
                              hipStream_t stream) {
  (void)in_sizes; (void)n_in; (void)out_size; (void)ws_size;
  const float* query = (const float*)d_in[0];
  const float* key   = (const float*)d_in[1];
  const float* value = (const float*)d_in[2];
  const float* Wq = (const float*)d_in[3];
  const float* bq = (const float*)d_in[4];
  const float* Wk = (const float*)d_in[5];
  const float* bk = (const float*)d_in[6];
  const float* Wv = (const float*)d_in[7];
  const float* bv = (const float*)d_in[8];
  const float* Wo = (const float*)d_in[9];
  const float* bo = (const float*)d_in[10];
  const float* tbl = (const float*)d_in[11];

  const size_t per = (size_t)B_SZ * H_NUM * S_LEN * HD;   // 4,194,304 elems
  const size_t wsz = (size_t)E_DIM * E_DIM;               // 1,048,576 elems
  unsigned short* p = (unsigned short*)d_ws;
  unsigned short* wsQb = p; p += per;
  unsigned short* wsKb = p; p += per;
  unsigned short* wsVb = p; p += per;
  unsigned short* wsRb = p; p += 131072;
  unsigned short* wsXq = p; p += per;
  unsigned short* wsXk = p; p += per;
  unsigned short* wsXv = p; p += per;
  unsigned short* wsWq = p; p += wsz;
  unsigned short* wsWk = p; p += wsz;
  unsigned short* wsWv = p; p += wsz;
  unsigned short* wsWo = p; p += wsz;
  unsigned short* wsA  = p; p += per;      // attn out bf16
  float* out = (float*)d_out;

  dim3 blk(256);
  hipLaunchKernelGGL(conv_all, dim3(8256), blk, 0, stream,
                     query, key, value, Wq, Wk, Wv, Wo, tbl,
                     wsXq, wsXk, wsXv, wsWq, wsWk, wsWv, wsWo, wsRb);
  hipLaunchKernelGGL(qkv_mfma, dim3(32, 8, 3), blk, 0, stream,
                     wsXq, wsXk, wsXv, wsWq, wsWk, wsWv, bq, bk, bv,
                     wsQb, wsKb, wsVb);
  hipLaunchKernelGGL(attn_mfma, dim3(1024), blk, 0, stream,
                     wsQb, wsKb, wsVb, wsRb, wsA);
  hipLaunchKernelGGL(outp_mfma, dim3(32, 8), blk, 0, stream,
                     wsA, wsWo, bo, out);
}